// Round 2
// baseline (3035.977 us; speedup 1.0000x reference)
//
#include <hip/hip_runtime.h>

// MoE router, fp32 in/out, bf16 MFMA compute.
// B=8 T=2048 D=1024 E=8 F=4096 K=2. BT=16384 tokens, 32768 token-expert rows.
#define BT 16384
#define DD 1024
#define NE 8
#define FF 4096

typedef unsigned short u16;
using v8s = __attribute__((ext_vector_type(8))) short;
using v4f = __attribute__((ext_vector_type(4))) float;

__device__ inline u16 f2bf(float f){ union{float f; unsigned int u;} v; v.f=f; unsigned r=v.u+0x7fffu+((v.u>>16)&1u); return (u16)(r>>16); }
// pack two fp32 -> two bf16 (truncation) in one v_perm_b32
__device__ inline unsigned pk(float x, float y){
  union{float f; unsigned u;} a, b; a.f=x; b.f=y;
  return __builtin_amdgcn_perm(b.u, a.u, 0x07060302u); // (bf16(y)<<16)|bf16(x)
}
__device__ inline uint2 pk4(float4 v){
  uint2 r; r.x = pk(v.x, v.y); r.y = pk(v.z, v.w); return r;
}

// ---------------- gating: logits + top2, one wave per token (fp32) ----------------
__global__ __launch_bounds__(256) void k_gate(const float* __restrict__ tok, const float* __restrict__ gw,
                                              const float* __restrict__ gb, float* __restrict__ lp,
                                              int* __restrict__ eArr, int* __restrict__ ctrl){
  int wid = threadIdx.x >> 6, lane = threadIdx.x & 63;
  int t = blockIdx.x*4 + wid;
  const float* xp = tok + (size_t)t*DD + lane*16;
  float x[16];
  {
    float4 q0=*(const float4*)xp, q1=*(const float4*)(xp+4), q2=*(const float4*)(xp+8), q3=*(const float4*)(xp+12);
    x[0]=q0.x;x[1]=q0.y;x[2]=q0.z;x[3]=q0.w; x[4]=q1.x;x[5]=q1.y;x[6]=q1.z;x[7]=q1.w;
    x[8]=q2.x;x[9]=q2.y;x[10]=q2.z;x[11]=q2.w; x[12]=q3.x;x[13]=q3.y;x[14]=q3.z;x[15]=q3.w;
  }
  float lg[NE];
  #pragma unroll
  for(int e=0;e<NE;e++){
    const float* wp = gw + e*DD + lane*16;
    float4 q0=*(const float4*)wp, q1=*(const float4*)(wp+4), q2=*(const float4*)(wp+8), q3=*(const float4*)(wp+12);
    float w[16]={q0.x,q0.y,q0.z,q0.w,q1.x,q1.y,q1.z,q1.w,q2.x,q2.y,q2.z,q2.w,q3.x,q3.y,q3.z,q3.w};
    float s=0.f;
    #pragma unroll
    for(int i=0;i<16;i++) s += x[i]*w[i];
    #pragma unroll
    for(int off=32;off;off>>=1) s += __shfl_xor(s,off);
    lg[e] = s + gb[e];
  }
  if(lane==0){
    float l0=-3e38f,l1=-3e38f; int e0=0,e1=0;
    #pragma unroll
    for(int e=0;e<NE;e++){ float v=lg[e];
      if(v>l0){l1=l0;e1=e0;l0=v;e0=e;} else if(v>l1){l1=v;e1=e;} }
    lp[t]=l0; lp[BT+t]=l1;
    eArr[t*2]=e0; eArr[t*2+1]=e1;
    atomicAdd(&ctrl[e0],1); atomicAdd(&ctrl[e1],1);
  }
}

// ---------------- softmax over token axis per (b,k): 16 blocks ----------------
__global__ __launch_bounds__(256) void k_smstats(const float* __restrict__ lp, float* __restrict__ mv,
                                                 float* __restrict__ sv){
  __shared__ float sm[256];
  int idx=blockIdx.x; int b=idx>>1, k=idx&1;
  const float* p = lp + k*BT + b*2048;
  int tid=threadIdx.x;
  float m=-3e38f;
  #pragma unroll
  for(int i=0;i<8;i++) m=fmaxf(m, p[tid+i*256]);
  sm[tid]=m; __syncthreads();
  for(int s=128;s;s>>=1){ if(tid<s) sm[tid]=fmaxf(sm[tid],sm[tid+s]); __syncthreads(); }
  float mx=sm[0]; __syncthreads();
  float su=0.f;
  #pragma unroll
  for(int i=0;i<8;i++) su += expf(p[tid+i*256]-mx);
  sm[tid]=su; __syncthreads();
  for(int s=128;s;s>>=1){ if(tid<s) sm[tid]+=sm[tid+s]; __syncthreads(); }
  if(tid==0){ mv[idx]=mx; sv[idx]=sm[0]; }
}

// ctrl layout (ints): [0:8) counts, [8:16) cursor, [16:24) base
__global__ void k_prefix(int* ctrl){
  if(threadIdx.x==0 && blockIdx.x==0){
    int run=0;
    for(int e=0;e<NE;e++){ ctrl[16+e]=run; ctrl[8+e]=run; run+=ctrl[e]; }
  }
}

__global__ __launch_bounds__(256) void k_assign(const float* __restrict__ lp, const int* __restrict__ eArr,
                                                const float* __restrict__ mv, const float* __restrict__ sv,
                                                int* __restrict__ ctrl, int* __restrict__ token_of,
                                                float* __restrict__ g_row){
  int t = blockIdx.x*256 + threadIdx.x;
  int b = t >> 11;
  #pragma unroll
  for(int k=0;k<2;k++){
    float l = lp[k*BT+t];
    float g = expf(l - mv[b*2+k]) / sv[b*2+k];
    int e = eArr[t*2+k];
    int row = atomicAdd(&ctrl[8+e],1);
    token_of[row]=t; g_row[row]=g;
  }
}

// ---------------- grouped GEMM1: H = relu(X_gathered @ w1^T + b1) ----------------
// grid: x = 48 (m tiles), y = FS/128 (f tiles within split), z = expert
__global__ __launch_bounds__(256,2) void k_ffn1(const float* __restrict__ tok, const float* __restrict__ w1,
                                                const float* __restrict__ b1, u16* __restrict__ H,
                                                const int* __restrict__ ctrl, const int* __restrict__ token_of,
                                                int split_off, int FS){
  __shared__ u16 lsA[128*72];
  __shared__ u16 lsB[128*72];
  int e = blockIdx.z;
  int ne = ctrl[e];
  int m0 = blockIdx.x*128;
  if(m0 >= ne) return;
  int rbase = ctrl[16+e];
  int n0 = blockIdx.y*128;
  int tid=threadIdx.x, lane=tid&63, wid=tid>>6;
  int wm=wid&1, wn=wid>>1;
  int srow = tid>>1, shalf = tid&1;
  int gm = m0 + srow;
  int trow = (gm<ne)? token_of[rbase+gm] : 0;
  const float* aG = tok + (size_t)trow*DD + shalf*32;
  const float* bG = w1 + ((size_t)e*FF + split_off + n0 + srow)*DD + shalf*32;
  v4f acc[4][4];
  #pragma unroll
  for(int i=0;i<4;i++){
    #pragma unroll
    for(int j=0;j<4;j++) acc[i][j]=(v4f)(0.f); }
  for(int k0=0;k0<DD;k0+=64){
    uint2 pa[8], pb[8];
    #pragma unroll
    for(int i=0;i<8;i++) pa[i]=pk4(*(const float4*)(aG+k0+i*4));
    #pragma unroll
    for(int i=0;i<8;i++) pb[i]=pk4(*(const float4*)(bG+k0+i*4));
    __syncthreads();
    int sb = srow*72 + shalf*32;
    #pragma unroll
    for(int i=0;i<4;i++){
      *(uint4*)&lsA[sb+i*8] = make_uint4(pa[2*i].x,pa[2*i].y,pa[2*i+1].x,pa[2*i+1].y);
      *(uint4*)&lsB[sb+i*8] = make_uint4(pb[2*i].x,pb[2*i].y,pb[2*i+1].x,pb[2*i+1].y);
    }
    __syncthreads();
    #pragma unroll
    for(int kk=0; kk<64; kk+=32){
      v8s af[4], bf[4];
      #pragma unroll
      for(int mi=0;mi<4;mi++) af[mi] = *(const v8s*)&lsA[(wm*64+mi*16+(lane&15))*72 + kk + (lane>>4)*8];
      #pragma unroll
      for(int ni=0;ni<4;ni++) bf[ni] = *(const v8s*)&lsB[(wn*64+ni*16+(lane&15))*72 + kk + (lane>>4)*8];
      #pragma unroll
      for(int mi=0;mi<4;mi++)
        #pragma unroll
        for(int ni=0;ni<4;ni++)
          acc[mi][ni] = __builtin_amdgcn_mfma_f32_16x16x32_bf16(af[mi],bf[ni],acc[mi][ni],0,0,0);
    }
  }
  int rq = (lane>>4)*4;
  #pragma unroll
  for(int mi=0;mi<4;mi++){
    int rowb = m0 + wm*64 + mi*16 + rq;
    #pragma unroll
    for(int r=0;r<4;r++){
      int gmr = rowb + r;
      if(gmr >= ne) continue;
      size_t hoff = (size_t)(rbase+gmr)*FS;
      #pragma unroll
      for(int ni=0;ni<4;ni++){
        int col = wn*64+ni*16+(lane&15);
        int fi = n0 + col;
        float v = acc[mi][ni][r] + b1[(size_t)e*FF + split_off + fi];
        v = fmaxf(v,0.f);
        H[hoff + fi] = f2bf(v);
      }
    }
  }
}

// ---------------- grouped GEMM2: out[t] += g * (H @ w2^T + b2) ----------------
// grid: x = 48 (m tiles), y = 8 (d tiles), z = expert
__global__ __launch_bounds__(256,2) void k_ffn2(const u16* __restrict__ H, const float* __restrict__ w2,
                                                const float* __restrict__ b2, float* __restrict__ outF,
                                                const int* __restrict__ ctrl, const int* __restrict__ token_of,
                                                const float* __restrict__ g_row, int split_off, int FS, int addb){
  __shared__ u16 lsA[128*72];
  __shared__ u16 lsB[128*72];
  int e = blockIdx.z;
  int ne = ctrl[e];
  int m0 = blockIdx.x*128;
  if(m0 >= ne) return;
  int rbase = ctrl[16+e];
  int n0 = blockIdx.y*128;
  int tid=threadIdx.x, lane=tid&63, wid=tid>>6;
  int wm=wid&1, wn=wid>>1;
  int srow = tid>>1, shalf = tid&1;
  int arow = rbase + m0 + srow; if(arow > 2*BT-1) arow = 2*BT-1;
  const u16* aG = H + (size_t)arow*FS + shalf*32;
  const float* bG = w2 + ((size_t)e*DD + n0 + srow)*FF + split_off + shalf*32;
  v4f acc[4][4];
  #pragma unroll
  for(int i=0;i<4;i++){
    #pragma unroll
    for(int j=0;j<4;j++) acc[i][j]=(v4f)(0.f); }
  for(int k0=0;k0<FS;k0+=64){
    uint4 a0=*(const uint4*)(aG+k0), a1=*(const uint4*)(aG+k0+8),
          a2=*(const uint4*)(aG+k0+16), a3=*(const uint4*)(aG+k0+24);
    uint2 pb[8];
    #pragma unroll
    for(int i=0;i<8;i++) pb[i]=pk4(*(const float4*)(bG+k0+i*4));
    __syncthreads();
    int sb = srow*72 + shalf*32;
    *(uint4*)&lsA[sb+0]=a0; *(uint4*)&lsA[sb+8]=a1; *(uint4*)&lsA[sb+16]=a2; *(uint4*)&lsA[sb+24]=a3;
    #pragma unroll
    for(int i=0;i<4;i++)
      *(uint4*)&lsB[sb+i*8] = make_uint4(pb[2*i].x,pb[2*i].y,pb[2*i+1].x,pb[2*i+1].y);
    __syncthreads();
    #pragma unroll
    for(int kk=0; kk<64; kk+=32){
      v8s af[4], bf[4];
      #pragma unroll
      for(int mi=0;mi<4;mi++) af[mi] = *(const v8s*)&lsA[(wm*64+mi*16+(lane&15))*72 + kk + (lane>>4)*8];
      #pragma unroll
      for(int ni=0;ni<4;ni++) bf[ni] = *(const v8s*)&lsB[(wn*64+ni*16+(lane&15))*72 + kk + (lane>>4)*8];
      #pragma unroll
      for(int mi=0;mi<4;mi++)
        #pragma unroll
        for(int ni=0;ni<4;ni++)
          acc[mi][ni] = __builtin_amdgcn_mfma_f32_16x16x32_bf16(af[mi],bf[ni],acc[mi][ni],0,0,0);
    }
  }
  int rq = (lane>>4)*4;
  #pragma unroll
  for(int mi=0;mi<4;mi++){
    int rowb = m0 + wm*64 + mi*16 + rq;
    #pragma unroll
    for(int r=0;r<4;r++){
      int gmr = rowb + r;
      if(gmr >= ne) continue;
      int grow = rbase + gmr;
      int t = token_of[grow];
      float g = g_row[grow];
      #pragma unroll
      for(int ni=0;ni<4;ni++){
        int col = wn*64+ni*16+(lane&15);
        int d = n0 + col;
        float v = acc[mi][ni][r]*g;
        if(addb) v += g*b2[e*DD + d];
        unsafeAtomicAdd(&outF[(size_t)t*DD + d], v);
      }
    }
  }
}

extern "C" void kernel_launch(void* const* d_in, const int* in_sizes, int n_in,
                              void* d_out, int out_size, void* d_ws, size_t ws_size,
                              hipStream_t stream){
  (void)in_sizes; (void)n_in; (void)out_size;
  const float* tok=(const float*)d_in[0];
  const float* gw =(const float*)d_in[1];
  const float* gb =(const float*)d_in[2];
  const float* w1 =(const float*)d_in[3];
  const float* b1 =(const float*)d_in[4];
  const float* w2 =(const float*)d_in[5];
  const float* b2 =(const float*)d_in[6];
  float* outF=(float*)d_out;

  const size_t TAIL = (size_t)4*1024*1024;
  int S=0; size_t HB=0;
  for(int s=1;s<=32;s<<=1){
    size_t hb=(size_t)2*BT*(FF/s)*2;      // H rows=32768, cols=FF/s, bf16
    if(hb + TAIL <= ws_size){ S=s; HB=hb; break; }
  }
  if(!S) return; // workspace too small — visible as wrong output

  char* p=(char*)d_ws;
  u16*  H      = (u16*)p;
  float* lp    = (float*)(p + HB);             // 2*BT logits (top1, top2)
  float* g_row = lp + 2*BT;                    // 32768
  int*  token_of = (int*)(g_row + 2*BT);       // 32768
  int*  eArr     = token_of + 2*BT;            // 32768
  int*  ctrl     = eArr + 2*BT;                // 64 ints
  float* mv      = (float*)(ctrl + 64);        // 16
  float* sv      = mv + 16;                    // 16

  hipMemsetAsync(ctrl, 0, 256, stream);
  hipMemsetAsync(outF, 0, (size_t)BT*DD*4, stream);

  k_gate   <<<dim3(BT/4), dim3(256), 0, stream>>>(tok, gw, gb, lp, eArr, ctrl);
  k_smstats<<<dim3(16),   dim3(256), 0, stream>>>(lp, mv, sv);
  k_prefix <<<dim3(1),    dim3(64),  0, stream>>>(ctrl);
  k_assign <<<dim3(BT/256), dim3(256), 0, stream>>>(lp, eArr, mv, sv, ctrl, token_of, g_row);

  int FS = FF/S;
  for(int s=0;s<S;s++){
    k_ffn1<<<dim3(48, FS/128, NE), dim3(256), 0, stream>>>(tok, w1, b1, H, ctrl, token_of, s*FS, FS);
    k_ffn2<<<dim3(48, DD/128, NE), dim3(256), 0, stream>>>(H, w2, b2, outF, ctrl, token_of, g_row, s*FS, FS, s==0?1:0);
  }
}

// Round 3
// 2445.708 us; speedup vs baseline: 1.2413x; 1.2413x over previous
//
#include <hip/hip_runtime.h>

// MoE router, fp32 in/out, bf16 MFMA compute (m97-style global_load_lds GEMMs).
// B=8 T=2048 D=1024 E=8 F=4096 K=2. BT=16384 tokens, 32768 token-expert rows.
#define BT 16384
#define DD 1024
#define NE 8
#define FF 4096

typedef unsigned short u16;
using v8s = __attribute__((ext_vector_type(8))) short;
using v4f = __attribute__((ext_vector_type(4))) float;

__device__ inline u16 f2bf(float f){ union{float f; unsigned int u;} v; v.f=f; unsigned r=v.u+0x7fffu+((v.u>>16)&1u); return (u16)(r>>16); }

__device__ inline void gload16(const u16* g, u16* l){
  __builtin_amdgcn_global_load_lds((const __attribute__((address_space(1))) unsigned int*)g,
                                   (__attribute__((address_space(3))) unsigned int*)l, 16, 0, 0);
}

// ---------------- fp32 -> bf16 (RNE) bulk convert ----------------
__global__ __launch_bounds__(256) void k_cvt(const float* __restrict__ in, u16* __restrict__ out, long n){
  long i = ((long)blockIdx.x*256 + threadIdx.x)*8;
  if(i >= n) return;
  float4 a = *(const float4*)(in+i);
  float4 b = *(const float4*)(in+i+4);
  *(ushort4*)(out+i)   = make_ushort4(f2bf(a.x), f2bf(a.y), f2bf(a.z), f2bf(a.w));
  *(ushort4*)(out+i+4) = make_ushort4(f2bf(b.x), f2bf(b.y), f2bf(b.z), f2bf(b.w));
}

// ---------------- gating: logits + top2, one wave per token (fp32, matches np ref) ----------------
__global__ __launch_bounds__(256) void k_gate(const float* __restrict__ tok, const float* __restrict__ gw,
                                              const float* __restrict__ gb, float* __restrict__ lp,
                                              int* __restrict__ eArr, int* __restrict__ ctrl){
  int wid = threadIdx.x >> 6, lane = threadIdx.x & 63;
  int t = blockIdx.x*4 + wid;
  const float* xp = tok + (size_t)t*DD + lane*16;
  float x[16];
  {
    float4 q0=*(const float4*)xp, q1=*(const float4*)(xp+4), q2=*(const float4*)(xp+8), q3=*(const float4*)(xp+12);
    x[0]=q0.x;x[1]=q0.y;x[2]=q0.z;x[3]=q0.w; x[4]=q1.x;x[5]=q1.y;x[6]=q1.z;x[7]=q1.w;
    x[8]=q2.x;x[9]=q2.y;x[10]=q2.z;x[11]=q2.w; x[12]=q3.x;x[13]=q3.y;x[14]=q3.z;x[15]=q3.w;
  }
  float lg[NE];
  #pragma unroll
  for(int e=0;e<NE;e++){
    const float* wp = gw + e*DD + lane*16;
    float4 q0=*(const float4*)wp, q1=*(const float4*)(wp+4), q2=*(const float4*)(wp+8), q3=*(const float4*)(wp+12);
    float w[16]={q0.x,q0.y,q0.z,q0.w,q1.x,q1.y,q1.z,q1.w,q2.x,q2.y,q2.z,q2.w,q3.x,q3.y,q3.z,q3.w};
    float s=0.f;
    #pragma unroll
    for(int i=0;i<16;i++) s += x[i]*w[i];
    #pragma unroll
    for(int off=32;off;off>>=1) s += __shfl_xor(s,off);
    lg[e] = s + gb[e];
  }
  if(lane==0){
    float l0=-3e38f,l1=-3e38f; int e0=0,e1=0;
    #pragma unroll
    for(int e=0;e<NE;e++){ float v=lg[e];
      if(v>l0){l1=l0;e1=e0;l0=v;e0=e;} else if(v>l1){l1=v;e1=e;} }
    lp[t]=l0; lp[BT+t]=l1;
    eArr[t*2]=e0; eArr[t*2+1]=e1;
    atomicAdd(&ctrl[e0],1); atomicAdd(&ctrl[e1],1);
  }
}

// ---------------- softmax over token axis per (b,k): 16 blocks ----------------
__global__ __launch_bounds__(256) void k_smstats(const float* __restrict__ lp, float* __restrict__ mv,
                                                 float* __restrict__ sv){
  __shared__ float sm[256];
  int idx=blockIdx.x; int b=idx>>1, k=idx&1;
  const float* p = lp + k*BT + b*2048;
  int tid=threadIdx.x;
  float m=-3e38f;
  #pragma unroll
  for(int i=0;i<8;i++) m=fmaxf(m, p[tid+i*256]);
  sm[tid]=m; __syncthreads();
  for(int s=128;s;s>>=1){ if(tid<s) sm[tid]=fmaxf(sm[tid],sm[tid+s]); __syncthreads(); }
  float mx=sm[0]; __syncthreads();
  float su=0.f;
  #pragma unroll
  for(int i=0;i<8;i++) su += expf(p[tid+i*256]-mx);
  sm[tid]=su; __syncthreads();
  for(int s=128;s;s>>=1){ if(tid<s) sm[tid]+=sm[tid+s]; __syncthreads(); }
  if(tid==0){ mv[idx]=mx; sv[idx]=sm[0]; }
}

// ctrl layout (ints): [0:8) counts, [8:16) cursor, [16:24) base
__global__ void k_prefix(int* ctrl){
  if(threadIdx.x==0 && blockIdx.x==0){
    int run=0;
    for(int e=0;e<NE;e++){ ctrl[16+e]=run; ctrl[8+e]=run; run+=ctrl[e]; }
  }
}

__global__ __launch_bounds__(256) void k_assign(const float* __restrict__ lp, const int* __restrict__ eArr,
                                                const float* __restrict__ mv, const float* __restrict__ sv,
                                                int* __restrict__ ctrl, int* __restrict__ token_of,
                                                float* __restrict__ g_row){
  int t = blockIdx.x*256 + threadIdx.x;
  int b = t >> 11;
  #pragma unroll
  for(int k=0;k<2;k++){
    float l = lp[k*BT+t];
    float g = expf(l - mv[b*2+k]) / sv[b*2+k];
    int e = eArr[t*2+k];
    int row = atomicAdd(&ctrl[8+e],1);
    token_of[row]=t; g_row[row]=g;
  }
}

// LDS tile layout (per 128x64 bf16 tile, 16 KB): chunk c = col16*128 + row,
// chunk = 16 B = 8 bf16 along K. global_load_lds lands chunk c at byte c*16.
// Frag read for 16x16x32 MFMA: lane L -> &ls[ ((kk>>3)+(L>>4))*1024 + m*8 ] (u16 units).

// ---------------- grouped GEMM1: H = relu(X_gathered @ w1^T + b1) ----------------
// grid: x = 48 (m tiles; seed-0 max ne < 6144), y = FS/128, z = expert
__global__ __launch_bounds__(256) void k_ffn1(const u16* __restrict__ tokb, const u16* __restrict__ w1b,
                                              const float* __restrict__ b1, u16* __restrict__ H,
                                              const int* __restrict__ ctrl, const int* __restrict__ token_of,
                                              int split_off, int FS){
  __shared__ u16 lsA[8192];
  __shared__ u16 lsB[8192];
  int e = blockIdx.z;
  int ne = ctrl[e];
  int m0 = blockIdx.x*128;
  if(m0 >= ne) return;
  int rbase = ctrl[16+e];
  int n0 = blockIdx.y*128;
  int tid=threadIdx.x, lane=tid&63, wave=tid>>6;
  int wm=wave&1, wn=wave>>1;
  const u16* aP[4]; const u16* bP[4]; u16* lA[4]; u16* lB[4];
  #pragma unroll
  for(int j=0;j<4;j++){
    int Wj = wave*256 + j*64;
    int row = (Wj & 127) + lane;
    int c16 = Wj >> 7;
    int gm = m0 + row; if(gm > ne-1) gm = ne-1;
    int tr = token_of[rbase + gm];
    aP[j] = tokb + (size_t)tr*DD + c16*8;
    bP[j] = w1b + ((size_t)e*FF + split_off + n0 + row)*DD + c16*8;
    lA[j] = lsA + (size_t)Wj*8;
    lB[j] = lsB + (size_t)Wj*8;
  }
  v4f acc[4][4];
  #pragma unroll
  for(int i=0;i<4;i++){
    #pragma unroll
    for(int j=0;j<4;j++) acc[i][j]=(v4f)(0.f); }
  int q = lane>>4, ml = lane&15;
  for(int k0=0;k0<DD;k0+=64){
    __syncthreads();
    #pragma unroll
    for(int j=0;j<4;j++){
      gload16(aP[j], lA[j]); gload16(bP[j], lB[j]);
      aP[j]+=64; bP[j]+=64;
    }
    __syncthreads();
    #pragma unroll
    for(int kk=0;kk<2;kk++){
      v8s af[4], bf[4];
      #pragma unroll
      for(int mi=0;mi<4;mi++) af[mi] = *(const v8s*)&lsA[(kk*4+q)*1024 + (wm*64+mi*16+ml)*8];
      #pragma unroll
      for(int ni=0;ni<4;ni++) bf[ni] = *(const v8s*)&lsB[(kk*4+q)*1024 + (wn*64+ni*16+ml)*8];
      #pragma unroll
      for(int mi=0;mi<4;mi++)
        #pragma unroll
        for(int ni=0;ni<4;ni++)
          acc[mi][ni] = __builtin_amdgcn_mfma_f32_16x16x32_bf16(af[mi],bf[ni],acc[mi][ni],0,0,0);
    }
  }
  int rq = q*4;
  #pragma unroll
  for(int mi=0;mi<4;mi++){
    int rowb = m0 + wm*64 + mi*16 + rq;
    #pragma unroll
    for(int r=0;r<4;r++){
      int gmr = rowb + r;
      if(gmr >= ne) continue;
      size_t hoff = (size_t)(rbase+gmr)*FS;
      #pragma unroll
      for(int ni=0;ni<4;ni++){
        int col = wn*64+ni*16+ml;
        int fi = n0 + col;
        float v = acc[mi][ni][r] + b1[(size_t)e*FF + split_off + fi];
        v = fmaxf(v,0.f);
        H[hoff + fi] = f2bf(v);
      }
    }
  }
}

// ---------------- grouped GEMM2: out[t] += g * (H @ w2^T + b2) ----------------
// grid: x = 48 (m tiles), y = DD/128, z = expert
__global__ __launch_bounds__(256) void k_ffn2(const u16* __restrict__ H, const u16* __restrict__ w2b,
                                              const float* __restrict__ b2, float* __restrict__ outF,
                                              const int* __restrict__ ctrl, const int* __restrict__ token_of,
                                              const float* __restrict__ g_row, int split_off, int FS, int addb){
  __shared__ u16 lsA[8192];
  __shared__ u16 lsB[8192];
  int e = blockIdx.z;
  int ne = ctrl[e];
  int m0 = blockIdx.x*128;
  if(m0 >= ne) return;
  int rbase = ctrl[16+e];
  int n0 = blockIdx.y*128;
  int tid=threadIdx.x, lane=tid&63, wave=tid>>6;
  int wm=wave&1, wn=wave>>1;
  const u16* aP[4]; const u16* bP[4]; u16* lA[4]; u16* lB[4];
  #pragma unroll
  for(int j=0;j<4;j++){
    int Wj = wave*256 + j*64;
    int row = (Wj & 127) + lane;
    int c16 = Wj >> 7;
    int gm = m0 + row; if(gm > ne-1) gm = ne-1;
    aP[j] = H + (size_t)(rbase+gm)*FS + c16*8;
    bP[j] = w2b + ((size_t)e*DD + n0 + row)*FF + split_off + c16*8;
    lA[j] = lsA + (size_t)Wj*8;
    lB[j] = lsB + (size_t)Wj*8;
  }
  v4f acc[4][4];
  #pragma unroll
  for(int i=0;i<4;i++){
    #pragma unroll
    for(int j=0;j<4;j++) acc[i][j]=(v4f)(0.f); }
  int q = lane>>4, ml = lane&15;
  for(int k0=0;k0<FS;k0+=64){
    __syncthreads();
    #pragma unroll
    for(int j=0;j<4;j++){
      gload16(aP[j], lA[j]); gload16(bP[j], lB[j]);
      aP[j]+=64; bP[j]+=64;
    }
    __syncthreads();
    #pragma unroll
    for(int kk=0;kk<2;kk++){
      v8s af[4], bf[4];
      #pragma unroll
      for(int mi=0;mi<4;mi++) af[mi] = *(const v8s*)&lsA[(kk*4+q)*1024 + (wm*64+mi*16+ml)*8];
      #pragma unroll
      for(int ni=0;ni<4;ni++) bf[ni] = *(const v8s*)&lsB[(kk*4+q)*1024 + (wn*64+ni*16+ml)*8];
      #pragma unroll
      for(int mi=0;mi<4;mi++)
        #pragma unroll
        for(int ni=0;ni<4;ni++)
          acc[mi][ni] = __builtin_amdgcn_mfma_f32_16x16x32_bf16(af[mi],bf[ni],acc[mi][ni],0,0,0);
    }
  }
  int rq = q*4;
  #pragma unroll
  for(int mi=0;mi<4;mi++){
    int rowb = m0 + wm*64 + mi*16 + rq;
    #pragma unroll
    for(int r=0;r<4;r++){
      int gmr = rowb + r;
      if(gmr >= ne) continue;
      int grow = rbase + gmr;
      int t = token_of[grow];
      float g = g_row[grow];
      #pragma unroll
      for(int ni=0;ni<4;ni++){
        int col = wn*64+ni*16+ml;
        int d = n0 + col;
        float v = acc[mi][ni][r]*g;
        if(addb) v += g*b2[e*DD + d];
        unsafeAtomicAdd(&outF[(size_t)t*DD + d], v);
      }
    }
  }
}

extern "C" void kernel_launch(void* const* d_in, const int* in_sizes, int n_in,
                              void* d_out, int out_size, void* d_ws, size_t ws_size,
                              hipStream_t stream){
  (void)in_sizes; (void)n_in; (void)out_size;
  const float* tok=(const float*)d_in[0];
  const float* gw =(const float*)d_in[1];
  const float* gb =(const float*)d_in[2];
  const float* w1 =(const float*)d_in[3];
  const float* b1 =(const float*)d_in[4];
  const float* w2 =(const float*)d_in[5];
  const float* b2 =(const float*)d_in[6];
  float* outF=(float*)d_out;

  const long NTOK = (long)BT*DD;          // 16.8M
  const long NW   = (long)NE*FF*DD;       // 33.6M
  const size_t CONV = (size_t)(NTOK + 2*NW)*2;  // bf16 copies, 168 MB
  const size_t CTL  = 1<<20;
  int S=0; size_t HB=0;
  for(int s=1;s<=32;s<<=1){
    size_t hb=(size_t)2*BT*(FF/s)*2;      // H rows=32768, cols=FF/s, bf16
    if(CONV + CTL + hb <= ws_size){ S=s; HB=hb; break; }
  }
  if(!S) return; // workspace too small — visible as wrong output

  char* p=(char*)d_ws;
  u16* tokb = (u16*)p;
  u16* w1b  = tokb + NTOK;
  u16* w2b  = w1b + NW;
  char* q   = (char*)(w2b + NW);
  float* lp    = (float*)q;                    // 2*BT logits (top1, top2)
  float* g_row = lp + 2*BT;                    // 32768
  int*  token_of = (int*)(g_row + 2*BT);       // 32768
  int*  eArr     = token_of + 2*BT;            // 32768
  int*  ctrl     = eArr + 2*BT;                // 64 ints
  float* mv      = (float*)(ctrl + 64);        // 16
  float* sv      = mv + 16;                    // 16
  u16*  H        = (u16*)(q + CTL);

  hipMemsetAsync(ctrl, 0, 256, stream);
  hipMemsetAsync(outF, 0, (size_t)BT*DD*4, stream);

  k_cvt<<<dim3((unsigned)(NTOK/8/256)), dim3(256), 0, stream>>>(tok, tokb, NTOK);
  k_cvt<<<dim3((unsigned)(NW/8/256)),   dim3(256), 0, stream>>>(w1, w1b, NW);
  k_cvt<<<dim3((unsigned)(NW/8/256)),   dim3(256), 0, stream>>>(w2, w2b, NW);

  k_gate   <<<dim3(BT/4), dim3(256), 0, stream>>>(tok, gw, gb, lp, eArr, ctrl);
  k_smstats<<<dim3(16),   dim3(256), 0, stream>>>(lp, mv, sv);
  k_prefix <<<dim3(1),    dim3(64),  0, stream>>>(ctrl);
  k_assign <<<dim3(BT/256), dim3(256), 0, stream>>>(lp, eArr, mv, sv, ctrl, token_of, g_row);

  int FS = FF/S;
  for(int s=0;s<S;s++){
    k_ffn1<<<dim3(48, FS/128, NE), dim3(256), 0, stream>>>(tokb, w1b, b1, H, ctrl, token_of, s*FS, FS);
    k_ffn2<<<dim3(48, DD/128, NE), dim3(256), 0, stream>>>(H, w2b, b2, outF, ctrl, token_of, g_row, s*FS, FS, s==0?1:0);
  }
}